// Round 6
// baseline (240.323 us; speedup 1.0000x reference)
//
#include <hip/hip_runtime.h>
#include <stdint.h>

// SparseAttention MI355X bf16-MFMA pipeline. Output f32.
// QKV row-major [B*S][2304] bf16; V^T [B*H][64][2048] bf16 (vprep).
// Attention: CONSTANT-SHIFT softmax (p=exp(s-8), scores |s|<~3) -> partials
// over key-chunks are pure sums -> split-K for global heads + combine pass.
// R6: 128 q-rows/block (32 rows/wave, 2 subgroups): K-frags read once per
// tile and reused, 36 MFMA/wave/tile between barriers (was 18).
// MFMA 16x16x32 bf16 layouts (HW-verified): A[m=lane&15][k=quad*8+j],
// B[k=quad*8+j][n=lane&15], C/D col=lane&15 row=quad*4+reg.

#define NH 12
#define SQ 2048

typedef __bf16 bf16x8 __attribute__((ext_vector_type(8)));
typedef float f32x4 __attribute__((ext_vector_type(4)));

#define GLOAD_LDS16(g, l)                                                      \
  __builtin_amdgcn_global_load_lds(                                            \
      (__attribute__((address_space(1))) void*)(g),                            \
      (__attribute__((address_space(3))) void*)(l), 16, 0, 0)

__device__ __forceinline__ unsigned short bfbits(float f) {
  __bf16 h = (__bf16)f;
  return *(unsigned short*)&h;
}

// ---------------- prep: x->bf16 + both weight transposes (1 kernel) --------
__global__ __launch_bounds__(256) void prep(
    const float* __restrict__ x, unsigned short* __restrict__ xb,
    const float* __restrict__ w_attn, unsigned short* __restrict__ wattnT,
    const float* __restrict__ w_proj, unsigned short* __restrict__ wprojT) {
  const int bid = blockIdx.x, t = threadIdx.x;
  if (bid < 512) {                 // convert x: 8192*768 floats
    const int n4 = 8192 * 768 / 4;
    for (int i = bid * 256 + t; i < n4; i += 512 * 256) {
      float4 v = ((const float4*)x)[i];
      ((ushort4*)xb)[i] = make_ushort4(bfbits(v.x), bfbits(v.y), bfbits(v.z), bfbits(v.w));
    }
    return;
  }
  __shared__ float tile[32][33];
  const float* in; unsigned short* out; int K, N, tl;
  if (bid < 512 + 72 * 24) { in = w_attn; out = wattnT; K = 768; N = 2304; tl = bid - 512; }
  else                     { in = w_proj; out = wprojT; K = 768; N = 768;  tl = bid - 512 - 72 * 24; }
  const int tpr = N / 32;
  const int n0 = (tl % tpr) * 32, k0 = (tl / tpr) * 32;
  const int tx = t & 31, ty = t >> 5;
  for (int r = ty; r < 32; r += 8) tile[r][tx] = in[(size_t)(k0 + r) * N + n0 + tx];
  __syncthreads();
  for (int r = ty; r < 32; r += 8) out[(size_t)(n0 + r) * K + k0 + tx] = bfbits(tile[tx][r]);
}

// ---------------- vprep: V transpose + gcol gather (1 kernel) ----------------
__global__ __launch_bounds__(256) void vprep(const unsigned short* __restrict__ QKV,
                                             unsigned short* __restrict__ Vtb,
                                             unsigned short* __restrict__ Kg,
                                             unsigned short* __restrict__ VgT,
                                             int* __restrict__ gidx) {
  const int id = blockIdx.x, t = threadIdx.x;
  if (id < 1536) {                 // vtrans
    const int bh = id >> 5, b = bh / NH, h = bh % NH;
    const int s0 = (id & 31) * 64;
    __shared__ unsigned short T[64][72];
    const int r = t >> 2, c0 = (t & 3) * 16;
    const size_t src = (size_t)(b * SQ + s0 + r) * 2304 + 1536 + h * 64 + c0;
    *(uint4*)&T[r][c0]     = *(const uint4*)&QKV[src];
    *(uint4*)&T[r][c0 + 8] = *(const uint4*)&QKV[src + 8];
    __syncthreads();
    unsigned short pk[16];
#pragma unroll
    for (int z = 0; z < 16; ++z) pk[z] = T[c0 + z][r];
    size_t dst = (size_t)bh * 131072 + (size_t)r * 2048 + s0 + c0;
    *(uint4*)&Vtb[dst]     = *(uint4*)&pk[0];
    *(uint4*)&Vtb[dst + 8] = *(uint4*)&pk[8];
    return;
  }
  const int g = id - 1536;         // gather: 16 bh * 8 chunks
  const int bh = g >> 3, y = g & 7;
  const int b = bh >> 2, h = 8 + (bh & 3);
  if (g == 0) {
    int c = t;
    gidx[c] = (c < 203) ? (int)((double)c * (2047.0 / 203.0)) : ((c == 203) ? 2047 : -1);
  }
  {  // Kg rows from qkvb K-section
    int c = t, ch = y;
    int col = (c < 203) ? (int)((double)c * (2047.0 / 203.0)) : ((c == 203) ? 2047 : -1);
    uint4 v = {0u, 0u, 0u, 0u};
    if (col >= 0) v = *(const uint4*)&QKV[(size_t)(b * SQ + col) * 2304 + 768 + h * 64 + ch * 8];
    *(uint4*)&Kg[((size_t)bh * 256 + c) * 64 + ch * 8] = v;
  }
  {  // VgT directly from qkvb V-section (transpose gather)
    int d = t >> 2;
    int cb = (t & 3) * 64 + y * 8;
    for (int cc = 0; cc < 8; ++cc) {
      int c = cb + cc;
      int col = (c < 203) ? (int)((double)c * (2047.0 / 203.0)) : ((c == 203) ? 2047 : -1);
      unsigned short v = 0;
      if (col >= 0) v = QKV[(size_t)(b * SQ + col) * 2304 + 1536 + h * 64 + d];
      VgT[((size_t)bh * 64 + d) * 256 + c] = v;
    }
  }
}

// ---------------- GEMM mainloop (BM=BN=128, BK=32, async LDS DMA) ----------
__device__ __forceinline__ void gemm_mainloop(
    const unsigned short* __restrict__ A, const unsigned short* __restrict__ BT,
    int m0, int n0, int tid,
    unsigned short* As, unsigned short* Bs,   // 128 x 32 bf16, UNPADDED
    f32x4 acc[4][4]) {
  const int lane = tid & 63, wave = tid >> 6;
  const int wm = wave >> 1, wn = wave & 1;
  const int ln = lane & 15, quad = lane >> 4;
  const int arow = wave * 16 + (lane >> 2);
  const int acol = (lane & 3) * 8;

#pragma unroll
  for (int mi = 0; mi < 4; ++mi)
#pragma unroll
    for (int ni = 0; ni < 4; ++ni) acc[mi][ni] = (f32x4){0.f, 0.f, 0.f, 0.f};

  for (int kt = 0; kt < 24; ++kt) {
    const int k0 = kt * 32;
    __syncthreads();
#pragma unroll
    for (int p = 0; p < 2; ++p) {
      GLOAD_LDS16(A  + (size_t)(m0 + p * 64 + arow) * 768 + k0 + acol,
                  &As[(p * 64 + wave * 16) * 32]);
      GLOAD_LDS16(BT + (size_t)(n0 + p * 64 + arow) * 768 + k0 + acol,
                  &Bs[(p * 64 + wave * 16) * 32]);
    }
    __syncthreads();
    bf16x8 aF[4], bF[4];
#pragma unroll
    for (int mi = 0; mi < 4; ++mi) aF[mi] = *(const bf16x8*)&As[(wm * 64 + mi * 16 + ln) * 32 + quad * 8];
#pragma unroll
    for (int ni = 0; ni < 4; ++ni) bF[ni] = *(const bf16x8*)&Bs[(wn * 64 + ni * 16 + ln) * 32 + quad * 8];
#pragma unroll
    for (int mi = 0; mi < 4; ++mi)
#pragma unroll
      for (int ni = 0; ni < 4; ++ni)
        acc[mi][ni] = __builtin_amdgcn_mfma_f32_16x16x32_bf16(aF[mi], bF[ni], acc[mi][ni], 0, 0, 0);
  }
}

// ---------------- QKV GEMM: row-major bf16 out ----------------
__global__ __launch_bounds__(256) void qkv_gemm(
    const unsigned short* __restrict__ Xb, const unsigned short* __restrict__ WT,
    const float* __restrict__ bias, unsigned short* __restrict__ Out) {
  __shared__ __attribute__((aligned(16))) unsigned short As[128 * 32];
  __shared__ __attribute__((aligned(16))) unsigned short Bs[128 * 32];
  f32x4 acc[4][4];
  const int m0 = blockIdx.y * 128, n0 = blockIdx.x * 128;
  const int tid = threadIdx.x;
  gemm_mainloop(Xb, WT, m0, n0, tid, As, Bs, acc);
  const int lane = tid & 63, wave = tid >> 6;
  const int wm = wave >> 1, wn = wave & 1, ln = lane & 15, quad = lane >> 4;
#pragma unroll
  for (int mi = 0; mi < 4; ++mi)
#pragma unroll
    for (int ni = 0; ni < 4; ++ni) {
      int n = n0 + wn * 64 + ni * 16 + ln;
      float bs = bias[n];
#pragma unroll
      for (int rg = 0; rg < 4; ++rg) {
        int m = m0 + wm * 64 + mi * 16 + quad * 4 + rg;
        Out[(size_t)m * 2304 + n] = bfbits(acc[mi][ni][rg] + bs);
      }
    }
}

// ---------------- Proj GEMM: fp32 out ----------------
__global__ __launch_bounds__(256) void proj_gemm(
    const unsigned short* __restrict__ Ab, const unsigned short* __restrict__ WT,
    const float* __restrict__ bias, float* __restrict__ Out) {
  __shared__ __attribute__((aligned(16))) unsigned short As[128 * 32];
  __shared__ __attribute__((aligned(16))) unsigned short Bs[128 * 32];
  f32x4 acc[4][4];
  const int m0 = blockIdx.y * 128, n0 = blockIdx.x * 128;
  const int tid = threadIdx.x;
  gemm_mainloop(Ab, WT, m0, n0, tid, As, Bs, acc);
  const int lane = tid & 63, wave = tid >> 6;
  const int wm = wave >> 1, wn = wave & 1, ln = lane & 15, quad = lane >> 4;
#pragma unroll
  for (int mi = 0; mi < 4; ++mi)
#pragma unroll
    for (int ni = 0; ni < 4; ++ni)
#pragma unroll
      for (int rg = 0; rg < 4; ++rg) {
        int m = m0 + wm * 64 + mi * 16 + quad * 4 + rg;
        int n = n0 + wn * 64 + ni * 16 + ln;
        Out[(size_t)m * 768 + n] = acc[mi][ni][rg] + bias[n];
      }
}

// ---------------- Flash attention: 128 q-rows/block, split-K ----------------
// Grid 1120: [0,608) global parts (<=13 tiles), [608,1120) local (<=6).
// Global (bh16=gid/38): rem -> (qi,part); causal kb in [9p, min(9p+8, 2qi+1)],
// part 0 adds 4 gcol tiles. qi<=3 (single part) writes direct; else partials.
__global__ __launch_bounds__(256, 4) void attn_kernel(
    const unsigned short* __restrict__ QKV,   // [8192][2304]
    const unsigned short* __restrict__ Vtb,   // [48][64][2048]
    const unsigned short* __restrict__ Kg, const unsigned short* __restrict__ VgT,
    const int* __restrict__ gidx,
    unsigned short* __restrict__ AOut,        // [8192][768]
    unsigned short* __restrict__ Opart,       // [1024][128*64] bf16
    float* __restrict__ Lpart) {              // [1024][128]
  __shared__ __attribute__((aligned(16))) unsigned short Ks[64 * 72];  // also P
  __shared__ __attribute__((aligned(16))) unsigned short Vs[64 * 72];

  const int gid = blockIdx.x;
  int b, h, qi, kb_begin, kb_end, slot = 0;
  bool do_g = false, multi = false;
  if (gid < 608) {
    int bh = gid / 38, rem = gid % 38;
    b = bh >> 2; h = 8 + (bh & 3);
    int part;
    if (rem < 4)       { qi = rem; part = 0; }
    else if (rem < 14) { int z = rem - 4;  qi = 4 + (z >> 1); part = z & 1; }
    else if (rem < 26) { int z = rem - 14; int q3 = z / 3; qi = 9 + q3; part = z - 3 * q3; }
    else               { int z = rem - 26; qi = 13 + (z >> 2); part = z & 3; }
    kb_begin = 9 * part;
    kb_end = min(9 * part + 8, 2 * qi + 1);
    do_g = (part == 0);
    multi = (qi >= 4);
    slot = (bh * 16 + qi) * 4 + part;
  } else {
    int lid = gid - 608;
    int bh = lid >> 4; b = bh >> 3; h = bh & 7; qi = lid & 15;
    kb_begin = max(0, 2 * qi - 4); kb_end = 2 * qi + 1;
  }
  const int qb0 = qi * 128;
  const bool is_local = (h < 8);
  const int tid = threadIdx.x, lane = tid & 63, wave = tid >> 6;
  const int ln = lane & 15, quad = lane >> 4;
  const int bh48 = b * NH + h;
  const int bhg = (b << 2) | (h & 3);

  bf16x8 qA[2][2];
#pragma unroll
  for (int s = 0; s < 2; ++s) {
    const size_t qoff = (size_t)(b * SQ + qb0 + wave * 32 + s * 16 + ln) * 2304 + h * 64;
    qA[s][0] = *(const bf16x8*)&QKV[qoff + quad * 8];
    qA[s][1] = *(const bf16x8*)&QKV[qoff + 32 + quad * 8];
  }

  bf16x8 onesF;
#pragma unroll
  for (int z = 0; z < 8; ++z) onesF[z] = (__bf16)1.0f;

  f32x4 o[2][4], ls2[2];
#pragma unroll
  for (int s = 0; s < 2; ++s) {
    ls2[s] = (f32x4){0.f, 0.f, 0.f, 0.f};
#pragma unroll
    for (int dt = 0; dt < 4; ++dt) o[s][dt] = (f32x4){0.f, 0.f, 0.f, 0.f};
  }

  const int nc = kb_end - kb_begin + 1;
  const int ntiles = nc + (do_g ? 4 : 0);
  const int iw = qb0 + wave * 32;
  const int sr = tid >> 3, sch = tid & 7;

  for (int t = 0; t < ntiles; ++t) {
    const bool gph = (t >= nc);
    const int kstart = gph ? 0 : (kb_begin + t) * 64;
    const int kg0 = gph ? (t - nc) * 64 : 0;
    __syncthreads();  // all P/Vs reads from prev tile done
    if (!gph) {
#pragma unroll
      for (int p = 0; p < 2; ++p) {
        int row = p * 32 + sr;
        *(uint4*)&Ks[row * 72 + sch * 8] =
            *(const uint4*)&QKV[(size_t)(b * SQ + kstart + row) * 2304 + 768 + h * 64 + sch * 8];
        *(uint4*)&Vs[row * 72 + sch * 8] =
            *(const uint4*)&Vtb[(size_t)bh48 * 131072 + (size_t)row * 2048 + kstart + sch * 8];
      }
    } else {
#pragma unroll
      for (int p = 0; p < 2; ++p) {
        int row = p * 32 + sr;
        *(uint4*)&Ks[row * 72 + sch * 8] =
            *(const uint4*)&Kg[((size_t)bhg * 256 + kg0 + row) * 64 + sch * 8];
        *(uint4*)&Vs[row * 72 + sch * 8] =
            *(const uint4*)&VgT[((size_t)bhg * 64 + row) * 256 + kg0 + sch * 8];
      }
    }
    __syncthreads();

    float p2[2][4][4];
    const bool full = !gph && (kstart + 63 <= iw) && (!is_local || kstart >= iw - 225);
#pragma unroll
    for (int nt = 0; nt < 4; ++nt) {
      bf16x8 kF0 = *(const bf16x8*)&Ks[(nt * 16 + ln) * 72 + quad * 8];
      bf16x8 kF1 = *(const bf16x8*)&Ks[(nt * 16 + ln) * 72 + 32 + quad * 8];
#pragma unroll
      for (int s = 0; s < 2; ++s) {
        f32x4 c = (f32x4){0.f, 0.f, 0.f, 0.f};
        c = __builtin_amdgcn_mfma_f32_16x16x32_bf16(qA[s][0], kF0, c, 0, 0, 0);
        c = __builtin_amdgcn_mfma_f32_16x16x32_bf16(qA[s][1], kF1, c, 0, 0, 0);
        if (full) {
#pragma unroll
          for (int rg = 0; rg < 4; ++rg) p2[s][nt][rg] = __expf(c[rg] * 0.125f - 8.f);
        } else if (!gph) {
          int j = kstart + nt * 16 + ln;
#pragma unroll
          for (int rg = 0; rg < 4; ++rg) {
            int i = iw + s * 16 + quad * 4 + rg;
            bool ok = is_local ? (j >= i - 256 && j <= i) : (j <= i);
            p2[s][nt][rg] = ok ? __expf(c[rg] * 0.125f - 8.f) : 0.f;
          }
        } else {
          int jg = gidx[kg0 + nt * 16 + ln];
#pragma unroll
          for (int rg = 0; rg < 4; ++rg) {
            bool ok = jg > (iw + s * 16 + quad * 4 + rg);
            p2[s][nt][rg] = ok ? __expf(c[rg] * 0.125f - 8.f) : 0.f;
          }
        }
      }
    }
    __syncthreads();  // all waves done reading Ks -> reuse as P (16 rows/wave)

    __bf16* P = (__bf16*)Ks;
#pragma unroll
    for (int s = 0; s < 2; ++s) {
#pragma unroll
      for (int rg = 0; rg < 4; ++rg) {
        int prow = (wave * 16 + quad * 4 + rg) * 72;
#pragma unroll
        for (int nt = 0; nt < 4; ++nt)
          P[prow + nt * 16 + ln] = (__bf16)p2[s][nt][rg];
      }
      // same-wave DS in-order: reads below see this subgroup's writes; next
      // subgroup's overwrite (WAR) also safe.
      bf16x8 pF0 = *(const bf16x8*)&Ks[(wave * 16 + ln) * 72 + quad * 8];
      bf16x8 pF1 = *(const bf16x8*)&Ks[(wave * 16 + ln) * 72 + 32 + quad * 8];
      ls2[s] = __builtin_amdgcn_mfma_f32_16x16x32_bf16(pF0, onesF, ls2[s], 0, 0, 0);
      ls2[s] = __builtin_amdgcn_mfma_f32_16x16x32_bf16(pF1, onesF, ls2[s], 0, 0, 0);
#pragma unroll
      for (int dt = 0; dt < 4; ++dt) {
        bf16x8 vF0 = *(const bf16x8*)&Vs[(dt * 16 + ln) * 72 + quad * 8];
        bf16x8 vF1 = *(const bf16x8*)&Vs[(dt * 16 + ln) * 72 + 32 + quad * 8];
        o[s][dt] = __builtin_amdgcn_mfma_f32_16x16x32_bf16(pF0, vF0, o[s][dt], 0, 0, 0);
        o[s][dt] = __builtin_amdgcn_mfma_f32_16x16x32_bf16(pF1, vF1, o[s][dt], 0, 0, 0);
      }
    }
  }

  if (gid >= 608 || !multi) {  // direct write (locals + single-part globals)
#pragma unroll
    for (int s = 0; s < 2; ++s)
#pragma unroll
      for (int dt = 0; dt < 4; ++dt)
#pragma unroll
        for (int rg = 0; rg < 4; ++rg) {
          int row = b * SQ + qb0 + wave * 32 + s * 16 + quad * 4 + rg;
          int e = h * 64 + dt * 16 + ln;
          AOut[(size_t)row * 768 + e] = bfbits(o[s][dt][rg] / ls2[s][rg]);
        }
  } else {  // multi-part global: partials
#pragma unroll
    for (int s = 0; s < 2; ++s) {
#pragma unroll
      for (int dt = 0; dt < 4; ++dt)
#pragma unroll
        for (int rg = 0; rg < 4; ++rg) {
          int row = wave * 32 + s * 16 + quad * 4 + rg;
          Opart[(size_t)slot * 8192 + row * 64 + dt * 16 + ln] = bfbits(o[s][dt][rg]);
        }
      if (ln == 0) {
#pragma unroll
        for (int rg = 0; rg < 4; ++rg)
          Lpart[(size_t)slot * 128 + wave * 32 + s * 16 + quad * 4 + rg] = ls2[s][rg];
      }
    }
  }
}

// ---------------- combine split-K partials (global heads, qi>=4) ------------
__global__ __launch_bounds__(256) void combine_parts(
    const unsigned short* __restrict__ Opart, const float* __restrict__ Lpart,
    unsigned short* __restrict__ AOut) {
  const int bid = blockIdx.x;        // 192 = 16 bh * 12 (qi-4)
  const int bh = bid / 12, qi = bid % 12 + 4;
  const int b = bh >> 2, h = 8 + (bh & 3);
  const int np = (qi <= 8) ? 2 : ((qi <= 12) ? 3 : 4);
  const int t = threadIdx.x, r = t >> 1, c0 = (t & 1) * 32;
  const int slot0 = (bh * 16 + qi) * 4;
  float acc[32];
#pragma unroll
  for (int z = 0; z < 32; ++z) acc[z] = 0.f;
  float l = 0.f;
  for (int p = 0; p < np; ++p) {
    const unsigned short* src = &Opart[(size_t)(slot0 + p) * 8192 + r * 64 + c0];
#pragma unroll
    for (int q = 0; q < 4; ++q) {
      bf16x8 v = *(const bf16x8*)&src[q * 8];
#pragma unroll
      for (int z = 0; z < 8; ++z) acc[q * 8 + z] += (float)v[z];
    }
    l += Lpart[(size_t)(slot0 + p) * 128 + r];
  }
  float inv = 1.f / l;
  unsigned short pk[32];
#pragma unroll
  for (int z = 0; z < 32; ++z) pk[z] = bfbits(acc[z] * inv);
  size_t dst = (size_t)(b * SQ + qi * 128 + r) * 768 + h * 64 + c0;
#pragma unroll
  for (int q = 0; q < 4; ++q) *(uint4*)&AOut[dst + q * 8] = *(uint4*)&pk[q * 8];
}

// ---------------- launch ----------------
extern "C" void kernel_launch(void* const* d_in, const int* in_sizes, int n_in,
                              void* d_out, int out_size, void* d_ws, size_t ws_size,
                              hipStream_t stream) {
  const float* x      = (const float*)d_in[0];
  const float* w_attn = (const float*)d_in[1];
  const float* b_attn = (const float*)d_in[2];
  const float* w_proj = (const float*)d_in[3];
  const float* b_proj = (const float*)d_in[4];
  float* out = (float*)d_out;

  char* ws = (char*)d_ws;
  size_t off = 0;
  auto alloc = [&](size_t bytes) {
    void* p = ws + off;
    off += (bytes + 255) & ~(size_t)255;
    return p;
  };
  unsigned short* xb     = (unsigned short*)alloc((size_t)8192 * 768 * 2);   // reused as attn buf
  unsigned short* wattnT = (unsigned short*)alloc((size_t)2304 * 768 * 2);
  unsigned short* wprojT = (unsigned short*)alloc((size_t)768 * 768 * 2);
  unsigned short* qkvb   = (unsigned short*)alloc((size_t)8192 * 2304 * 2);
  unsigned short* Vtb    = (unsigned short*)alloc((size_t)48 * 64 * 2048 * 2);
  unsigned short* Kgb    = (unsigned short*)alloc((size_t)16 * 256 * 64 * 2);
  unsigned short* VgTb   = (unsigned short*)alloc((size_t)16 * 64 * 256 * 2);
  int* gidxb             = (int*)alloc((size_t)256 * 4);
  unsigned short* Opartb = (unsigned short*)alloc((size_t)1024 * 8192 * 2);
  float* Lpartb          = (float*)alloc((size_t)1024 * 128 * 4);
  unsigned short* attnb  = xb;  // xb dead after qkv_gemm

  prep<<<dim3(512 + 72 * 24 + 24 * 24), dim3(256), 0, stream>>>(
      x, xb, w_attn, wattnT, w_proj, wprojT);
  qkv_gemm<<<dim3(18, 64), dim3(256), 0, stream>>>(xb, wattnT, b_attn, qkvb);
  vprep<<<dim3(1536 + 128), dim3(256), 0, stream>>>(qkvb, Vtb, Kgb, VgTb, gidxb);
  attn_kernel<<<dim3(1120), dim3(256), 0, stream>>>(qkvb, Vtb, Kgb, VgTb, gidxb,
                                                    attnb, Opartb, Lpartb);
  combine_parts<<<dim3(192), dim3(256), 0, stream>>>(Opartb, Lpartb, attnb);
  proj_gemm<<<dim3(6, 64), dim3(256), 0, stream>>>(attnb, wprojT, b_proj, out);
}